// Round 8
// baseline (557.359 us; speedup 1.0000x reference)
//
#include <hip/hip_runtime.h>
#include <hip/hip_cooperative_groups.h>

namespace cg = cooperative_groups;

#define C_CLUST 8
#define N_PAT   16384
#define D_FEAT  1024
#define DQ_DIM  128
#define K_TOP   128

// 1/sqrt(128) and 1/sqrt(1024)
#define INV_S128 0.08838834764831844055
#define INV_S1024 0.03125

// ---------- helpers ----------
__device__ inline unsigned f2key(float f) {
    unsigned u = __float_as_uint(f);
    return (u & 0x80000000u) ? ~u : (u | 0x80000000u);
}
__device__ inline float key2f(unsigned k) {
    unsigned u = (k & 0x80000000u) ? (k ^ 0x80000000u) : ~k;
    return __uint_as_float(u);
}

// ---------- single cooperative kernel, 7 phases ----------
// grid = 512 blocks x 256 threads. __launch_bounds__(256,2): VGPR<=256, LDS ~27KB
// -> >=2 blocks/CU resident -> 512 co-resident blocks guaranteed.
__global__ __launch_bounds__(256, 2) void mega_kernel(
    const float* __restrict__ feats,      // [C,N,D]
    const float* __restrict__ key_feats,  // [C,1,D]
    const float* __restrict__ Wq,         // [D,DQ]
    const float* __restrict__ bq,         // [DQ]
    const float* __restrict__ Wv,         // [D,D]
    const float* __restrict__ bv,         // [D]
    float* __restrict__ out,              // [C*K*D + C*D]
    char* __restrict__ ws)
{
    cg::grid_group grid = cg::this_grid();
    const int b   = blockIdx.x;            // 0..511
    const int tid = threadIdx.x;           // 0..255
    const int lane = tid & 63, wvid = tid >> 6;

    float*  scores  = (float*)(ws + 0);         // 524288 B
    double* qk_part = (double*)(ws + 524288);   // 131072
    double* r       = (double*)(ws + 655360);   // 65536
    double* b0      = (double*)(ws + 720896);   // 64
    int*    top_idx = (int*)(ws + 720960);      // 4096
    double* Aw      = (double*)(ws + 725056);   // 8192
    double* w_part  = (double*)(ws + 733248);   // 262144
    unsigned long long* cand = (unsigned long long*)(ws + 995392);  // 8*2048*8 = 131072
    unsigned* mxkey = (unsigned*)(ws + 1126464);                    // 8*16*4 = 512
    double*   Ssum  = (double*)(ws + 1126976);                      // 8*16*8 = 1024

    __shared__ unsigned long long su[2048];    // 16 KB: P4 (1024) / P5 (2048) sort buffer
    __shared__ double sdbl[D_FEAT];            // 8 KB: P7 w_lds
    __shared__ double partl[2][128];           // 2 KB: P5 pd / P7 partials
    __shared__ unsigned sred_u[4];
    __shared__ double sred_d[4];
    __shared__ double sZ;
    __shared__ double sa_g[32];
    __shared__ int sidx_g[32];

    // ================= P1: qk partials (blocks 0..127: c*16+sg) =================
    if (b < 128 && tid < 128) {
        const int c = b >> 4, sg = b & 15;
        const int d0 = sg * 64;
        double acc = 0.0;
#pragma unroll 4
        for (int d = d0; d < d0 + 64; ++d)
            acc += (double)key_feats[c * D_FEAT + d] * (double)Wq[d * DQ_DIM + tid];
        qk_part[(size_t)(c * 16 + sg) * DQ_DIM + tid] = acc;
    }
    grid.sync();

    // ================= P2: r[c][d] + b0[c] (wave per 4 d's) =================
    {
        const int gw = b * 4 + wvid;           // 0..2047; 256 waves per cluster
        const int c = gw >> 8;
        double q0 = (double)bq[lane], q1 = (double)bq[64 + lane];
#pragma unroll
        for (int sg = 0; sg < 16; ++sg) {
            q0 += qk_part[(size_t)(c * 16 + sg) * DQ_DIM + lane];
            q1 += qk_part[(size_t)(c * 16 + sg) * DQ_DIM + 64 + lane];
        }
#pragma unroll
        for (int t = 0; t < 4; ++t) {
            const int d = (gw & 255) * 4 + t;
            double a = (double)Wq[d * DQ_DIM + lane] * q0
                     + (double)Wq[d * DQ_DIM + 64 + lane] * q1;
#pragma unroll
            for (int o = 32; o > 0; o >>= 1) a += __shfl_xor(a, o, 64);
            if (lane == 0) r[c * D_FEAT + d] = a;
        }
        if ((gw & 255) == 0) {                 // b0 = bq . qk
            double p = (double)bq[lane] * q0 + (double)bq[64 + lane] * q1;
#pragma unroll
            for (int o = 32; o > 0; o >>= 1) p += __shfl_xor(p, o, 64);
            if (lane == 0) b0[c] = p;
        }
    }
    grid.sync();

    // ================= P3: scores (wave per 64 rows, r in VGPRs) =================
    {
        const int gw = b * 4 + wvid;           // 0..2047
        const int c = gw >> 8;
        const int n0 = (gw & 255) * 64;
        const double* rp = r + c * D_FEAT;
        double rr[16];
#pragma unroll
        for (int it = 0; it < 4; ++it)
#pragma unroll
            for (int j = 0; j < 4; ++j)
                rr[it * 4 + j] = rp[it * 256 + lane * 4 + j];
        const double bb = b0[c];
        const float4* fbase = (const float4*)(feats + (size_t)(c * N_PAT + n0) * D_FEAT);
        float* sout = scores + c * N_PAT + n0;

        for (int rI = 0; rI < 64; rI += 2) {
            const float4* fp0 = fbase + (size_t)(rI + 0) * 256;
            const float4* fp1 = fbase + (size_t)(rI + 1) * 256;
            double acc0 = 0.0, acc1 = 0.0;
#pragma unroll
            for (int it = 0; it < 4; ++it) {
                float4 f0 = fp0[it * 64 + lane];
                float4 f1 = fp1[it * 64 + lane];
                acc0 += (double)f0.x * rr[it * 4 + 0];
                acc0 += (double)f0.y * rr[it * 4 + 1];
                acc0 += (double)f0.z * rr[it * 4 + 2];
                acc0 += (double)f0.w * rr[it * 4 + 3];
                acc1 += (double)f1.x * rr[it * 4 + 0];
                acc1 += (double)f1.y * rr[it * 4 + 1];
                acc1 += (double)f1.z * rr[it * 4 + 2];
                acc1 += (double)f1.w * rr[it * 4 + 3];
            }
#pragma unroll
            for (int o = 32; o > 0; o >>= 1) {
                acc0 += __shfl_xor(acc0, o, 64);
                acc1 += __shfl_xor(acc1, o, 64);
            }
            if (lane == 0) {
                sout[rI + 0] = (float)(acc0 + bb);
                sout[rI + 1] = (float)(acc1 + bb);
            }
        }
    }
    grid.sync();

    // ========== P4: per-chunk bitonic top-128 + softmax partials (blocks 0..127) ==========
    if (b < 128) {
        const int c = b >> 4, chunk = b & 15;
        const int sbase = c * N_PAT + chunk * 1024;
        float sv[4];
        unsigned kmax = 0;
#pragma unroll
        for (int q = 0; q < 4; ++q) {
            const int li = q * 256 + tid;
            float s = scores[sbase + li];
            sv[q] = s;
            unsigned key = f2key(s);
            su[li] = ((unsigned long long)key << 32) | (unsigned)(~(unsigned)(chunk * 1024 + li));
            kmax = max(kmax, key);
        }
#pragma unroll
        for (int o = 32; o > 0; o >>= 1) kmax = max(kmax, __shfl_xor(kmax, o, 64));
        if (lane == 0) sred_u[wvid] = kmax;
        __syncthreads();
        kmax = max(max(sred_u[0], sred_u[1]), max(sred_u[2], sred_u[3]));
        const double mx_t = (double)key2f(kmax) * INV_S128;
        double es = 0.0;
#pragma unroll
        for (int q = 0; q < 4; ++q)
            es += (double)__expf((float)((double)sv[q] * INV_S128 - mx_t));
#pragma unroll
        for (int o = 32; o > 0; o >>= 1) es += __shfl_xor(es, o, 64);
        if (lane == 0) sred_d[wvid] = es;
        __syncthreads();
        if (tid == 0) {
            mxkey[c * 16 + chunk] = kmax;
            Ssum[c * 16 + chunk] = sred_d[0] + sred_d[1] + sred_d[2] + sred_d[3];
        }
        // bitonic sort 1024 keys descending (composite: val desc, idx asc)
        for (int k = 2; k <= 1024; k <<= 1) {
            for (int j = k >> 1; j > 0; j >>= 1) {
                __syncthreads();
                for (int i = tid; i < 1024; i += 256) {
                    int l = i ^ j;
                    if (l > i) {
                        unsigned long long a = su[i], bb2 = su[l];
                        bool desc = ((i & k) == 0);
                        if (desc ? (a < bb2) : (a > bb2)) { su[i] = bb2; su[l] = a; }
                    }
                }
            }
        }
        __syncthreads();
        if (tid < 128) cand[(size_t)(c * 16 + chunk) * 128 + tid] = su[tid];
    }
    grid.sync();

    // ========== P5: per-cluster merge 2048 candidates -> top-128, Aw (blocks 0..7) ==========
    if (b < 8) {
        const int c = b;
        for (int i = tid; i < 2048; i += 256) su[i] = cand[(size_t)c * 2048 + i];
        __syncthreads();
        for (int k = 2; k <= 2048; k <<= 1) {
            for (int j = k >> 1; j > 0; j >>= 1) {
                __syncthreads();
                for (int i = tid; i < 2048; i += 256) {
                    int l = i ^ j;
                    if (l > i) {
                        unsigned long long a = su[i], bb2 = su[l];
                        bool desc = ((i & k) == 0);
                        if (desc ? (a < bb2) : (a > bb2)) { su[i] = bb2; su[l] = a; }
                    }
                }
            }
        }
        __syncthreads();

        const unsigned mkey = (unsigned)(su[0] >> 32);      // global max score key
        const double m_t = (double)key2f(mkey) * INV_S128;
        double z = 0.0;
        if (tid < 16)
            z = Ssum[c * 16 + tid] *
                exp((double)key2f(mxkey[c * 16 + tid]) * INV_S128 - m_t);
        if (wvid == 0) {
#pragma unroll
            for (int o = 32; o > 0; o >>= 1) z += __shfl_xor(z, o, 64);
            if (tid == 0) sZ = z;
        }
        __syncthreads();
        const double Z = sZ;

        double* pd = (double*)partl;
        if (tid < K_TOP) {
            unsigned long long pr = su[tid];
            top_idx[c * K_TOP + tid] = (int)(~(unsigned)(pr & 0xFFFFFFFFull));
            double s = (double)key2f((unsigned)(pr >> 32));
            pd[tid] = exp(s * INV_S128 - m_t) / Z;
        }
        __syncthreads();
        if (tid < K_TOP) {
            double e = exp((pd[tid] - pd[0]) * INV_S1024);   // pd[0] is max (sorted)
            double se = e;
#pragma unroll
            for (int o = 32; o > 0; o >>= 1) se += __shfl_xor(se, o, 64);
            if (lane == 0) sred_d[wvid] = se;
        }
        __syncthreads();
        if (tid < K_TOP) {
            double tot = sred_d[0] + sred_d[1];
            double e = exp((pd[tid] - pd[0]) * INV_S1024);
            Aw[c * K_TOP + tid] = e / tot;
        }
    }
    grid.sync();

    // ========== P6: gather rows -> out + partial weighted sum (blocks 0..127) ==========
    if (b < 128) {
        const int c = b >> 4, quarter = (b >> 2) & 3, ich = b & 3;
        if (tid < 32) {
            sa_g[tid] = Aw[c * K_TOP + ich * 32 + tid];
            sidx_g[tid] = top_idx[c * K_TOP + ich * 32 + tid];
        }
        __syncthreads();
        const int d = quarter * 256 + tid;
        const float* fc = feats + (size_t)c * N_PAT * D_FEAT + d;
        float* oc = out + ((size_t)c * K_TOP + ich * 32) * D_FEAT + d;
        double a0 = 0.0, a1 = 0.0, a2 = 0.0, a3 = 0.0;
#pragma unroll 2
        for (int i = 0; i < 32; i += 4) {
            float v0 = fc[(size_t)sidx_g[i + 0] * D_FEAT];
            float v1 = fc[(size_t)sidx_g[i + 1] * D_FEAT];
            float v2 = fc[(size_t)sidx_g[i + 2] * D_FEAT];
            float v3 = fc[(size_t)sidx_g[i + 3] * D_FEAT];
            oc[(size_t)(i + 0) * D_FEAT] = v0;
            oc[(size_t)(i + 1) * D_FEAT] = v1;
            oc[(size_t)(i + 2) * D_FEAT] = v2;
            oc[(size_t)(i + 3) * D_FEAT] = v3;
            double aw0 = sa_g[i + 0], aw1 = sa_g[i + 1], aw2 = sa_g[i + 2], aw3 = sa_g[i + 3];
            a0 += aw0 * (double)v0;
            a1 += aw1 * (double)v1;
            a2 += aw2 * (double)v2;
            a3 += aw3 * (double)v3;
        }
        w_part[((size_t)(c * 4 + ich)) * D_FEAT + d] = (a0 + a1) + (a2 + a3);
    }
    grid.sync();

    // ========== P7: fusion = (sum w_part) @ Wv + bv (blocks 0..63) ==========
    if (b < 64) {
        const int c = b >> 3, dpg = b & 7;
        for (int d = tid; d < D_FEAT; d += 256) {
            double s = 0.0;
#pragma unroll
            for (int ich = 0; ich < 4; ++ich)
                s += w_part[((size_t)(c * 4 + ich)) * D_FEAT + d];
            sdbl[d] = s;
        }
        __syncthreads();
        const int dpl = tid & 127, half = tid >> 7;
        const int dp = dpg * 128 + dpl;
        const double* wc = sdbl + half * 512;
        const float* wvp = Wv + (size_t)(half * 512) * D_FEAT + dp;
        double a0 = 0.0, a1 = 0.0, a2 = 0.0, a3 = 0.0;
#pragma unroll 2
        for (int d = 0; d < 512; d += 4) {
            a0 += wc[d + 0] * (double)wvp[(size_t)(d + 0) * D_FEAT];
            a1 += wc[d + 1] * (double)wvp[(size_t)(d + 1) * D_FEAT];
            a2 += wc[d + 2] * (double)wvp[(size_t)(d + 2) * D_FEAT];
            a3 += wc[d + 3] * (double)wvp[(size_t)(d + 3) * D_FEAT];
        }
        partl[half][dpl] = (a0 + a1) + (a2 + a3);
        __syncthreads();
        if (half == 0) {
            double acc = (double)bv[dp] + partl[0][dpl] + partl[1][dpl];
            out[(size_t)(C_CLUST * K_TOP * D_FEAT) + c * D_FEAT + dp] = (float)acc;
        }
    }
}

extern "C" void kernel_launch(void* const* d_in, const int* in_sizes, int n_in,
                              void* d_out, int out_size, void* d_ws, size_t ws_size,
                              hipStream_t stream) {
    const float* feats     = (const float*)d_in[0];  // [8,16384,1024]
    const float* key_feats = (const float*)d_in[1];  // [8,1,1024]
    const float* Wq        = (const float*)d_in[2];  // [1024,128]
    const float* bq        = (const float*)d_in[3];  // [128]
    const float* Wv        = (const float*)d_in[4];  // [1024,1024]
    const float* bv        = (const float*)d_in[5];  // [1024]
    float* out = (float*)d_out;
    char* ws = (char*)d_ws;

    void* args[] = {
        (void*)&feats, (void*)&key_feats, (void*)&Wq, (void*)&bq,
        (void*)&Wv, (void*)&bv, (void*)&out, (void*)&ws
    };
    hipLaunchCooperativeKernel((const void*)mega_kernel,
                               dim3(512), dim3(256), args, 0, stream);
}

// Round 9
// 266.866 us; speedup vs baseline: 2.0885x; 2.0885x over previous
//
#include <hip/hip_runtime.h>

#define C_CLUST 8
#define N_PAT   16384
#define D_FEAT  1024
#define DQ_DIM  128
#define K_TOP   128

// 1/sqrt(128) and 1/sqrt(1024)
#define INV_S128 0.08838834764831844055
#define INV_S1024 0.03125

// ---------- helpers ----------
__device__ inline unsigned f2key(float f) {
    unsigned u = __float_as_uint(f);
    return (u & 0x80000000u) ? ~u : (u | 0x80000000u);
}
__device__ inline float key2f(unsigned k) {
    unsigned u = (k & 0x80000000u) ? (k ^ 0x80000000u) : ~k;
    return __uint_as_float(u);
}

// ============ kernel 1: per-block prep(qk,b0,r) + score chunk + chunk top-128 ============
// grid 128 blocks: b = c*16 + chunk ; 1024 threads (16 waves)
__global__ __launch_bounds__(1024) void scoreall_kernel(
    const float* __restrict__ feats,         // [C,N,D]
    const float* __restrict__ key_feats,     // [C,1,D]
    const float* __restrict__ Wq,            // [D,DQ]
    const float* __restrict__ bq,            // [DQ]
    unsigned long long* __restrict__ cand,   // [C][16][128]
    unsigned* __restrict__ mxkey,            // [C][16]
    double* __restrict__ Ssum)               // [C][16]
{
    const int b = blockIdx.x;
    const int c = b >> 4, chunk = b & 15;
    const int tid = threadIdx.x;
    const int lane = tid & 63, wv = tid >> 6;   // 16 waves

    __shared__ float keyrow[D_FEAT];            // 4 KB
    __shared__ double part[1024];               // 8 KB scratch (qk partials / r partials)
    __shared__ double qk_lds[DQ_DIM];           // 1 KB
    __shared__ double r_lds[D_FEAT];            // 8 KB
    __shared__ double b0_lds;
    __shared__ unsigned ured[16];
    __shared__ double dred[16];
    __shared__ unsigned bmax_s;
    __shared__ __align__(16) char ubuf[32768];  // phase A: Wq tile (32KB) | phase B: scores(4KB)+su(8KB)
    float* wq_tile  = (float*)ubuf;
    float* scores_s = (float*)ubuf;
    unsigned long long* su = (unsigned long long*)(ubuf + 4096);

    keyrow[tid] = key_feats[c * D_FEAT + tid];
    __syncthreads();

    // ---- qk[j] = key . Wq[:,j] + bq[j]  (8-way split-d partials) ----
    {
        const int j = tid & 127, s = tid >> 7;
        double acc = 0.0;
        for (int d = s; d < D_FEAT; d += 8)
            acc += (double)keyrow[d] * (double)Wq[d * DQ_DIM + j];
        part[s * DQ_DIM + j] = acc;
    }
    __syncthreads();
    if (tid < DQ_DIM) {
        double v = part[tid];
#pragma unroll
        for (int s2 = 1; s2 < 8; ++s2) v += part[s2 * DQ_DIM + tid];
        qk_lds[tid] = v + (double)bq[tid];
    }
    __syncthreads();
    if (wv == 0) {   // b0 = bq . qk
        double p = (double)bq[lane] * qk_lds[lane] + (double)bq[64 + lane] * qk_lds[64 + lane];
#pragma unroll
        for (int o = 32; o > 0; o >>= 1) p += __shfl_xor(p, o, 64);
        if (lane == 0) b0_lds = p;
    }

    // ---- r = Wq @ qk via 16 LDS-staged 64x128 tiles ----
    for (int ch = 0; ch < 16; ++ch) {
        __syncthreads();
        {   // coalesced tile load: 8192 f32 = 2 float4 per thread
            const float4* src = (const float4*)(Wq + (size_t)ch * 64 * DQ_DIM);
            float4* dst = (float4*)wq_tile;
            dst[tid * 2 + 0] = src[tid * 2 + 0];
            dst[tid * 2 + 1] = src[tid * 2 + 1];
        }
        __syncthreads();
        const int dloc = tid >> 4, jg = tid & 15;
        double acc = 0.0;
#pragma unroll
        for (int jj = 0; jj < 8; ++jj)
            acc += (double)wq_tile[dloc * DQ_DIM + jg * 8 + jj] * qk_lds[jg * 8 + jj];
        part[dloc * 16 + jg] = acc;
        __syncthreads();
        if (tid < 64) {
            double s = 0.0;
#pragma unroll
            for (int g = 0; g < 16; ++g) s += part[tid * 16 + g];
            r_lds[ch * 64 + tid] = s;
        }
    }
    __syncthreads();

    // ---- score phase: wave wv -> rows [chunk*1024 + wv*64, +64) ----
    const double bb = b0_lds;
    double rr[16];
#pragma unroll
    for (int it = 0; it < 4; ++it)
#pragma unroll
        for (int j = 0; j < 4; ++j)
            rr[it * 4 + j] = r_lds[it * 256 + lane * 4 + j];
    const int n0 = chunk * 1024 + wv * 64;
    const float4* fbase = (const float4*)(feats + (size_t)(c * N_PAT + n0) * D_FEAT);

    for (int rI = 0; rI < 64; rI += 2) {
        const float4* fp0 = fbase + (size_t)(rI + 0) * 256;
        const float4* fp1 = fbase + (size_t)(rI + 1) * 256;
        double acc0 = 0.0, acc1 = 0.0;
#pragma unroll
        for (int it = 0; it < 4; ++it) {
            float4 f0 = fp0[it * 64 + lane];
            float4 f1 = fp1[it * 64 + lane];
            acc0 += (double)f0.x * rr[it * 4 + 0];
            acc0 += (double)f0.y * rr[it * 4 + 1];
            acc0 += (double)f0.z * rr[it * 4 + 2];
            acc0 += (double)f0.w * rr[it * 4 + 3];
            acc1 += (double)f1.x * rr[it * 4 + 0];
            acc1 += (double)f1.y * rr[it * 4 + 1];
            acc1 += (double)f1.z * rr[it * 4 + 2];
            acc1 += (double)f1.w * rr[it * 4 + 3];
        }
#pragma unroll
        for (int o = 32; o > 0; o >>= 1) {
            acc0 += __shfl_xor(acc0, o, 64);
            acc1 += __shfl_xor(acc1, o, 64);
        }
        if (lane == 0) {
            scores_s[wv * 64 + rI + 0] = (float)(acc0 + bb);
            scores_s[wv * 64 + rI + 1] = (float)(acc1 + bb);
        }
    }
    __syncthreads();

    // ---- chunk top-128 + softmax partials ----
    const float sc = scores_s[tid];
    const unsigned key = f2key(sc);
    unsigned mk = key;
#pragma unroll
    for (int o = 32; o > 0; o >>= 1) mk = max(mk, __shfl_xor(mk, o, 64));
    if (lane == 0) ured[wv] = mk;
    __syncthreads();
    if (tid == 0) {
        unsigned m = ured[0];
        for (int i = 1; i < 16; ++i) m = max(m, ured[i]);
        bmax_s = m;
    }
    __syncthreads();
    const unsigned kmax = bmax_s;
    const double mx_t = (double)key2f(kmax) * INV_S128;
    double es = (double)__expf((float)((double)sc * INV_S128 - mx_t));
#pragma unroll
    for (int o = 32; o > 0; o >>= 1) es += __shfl_xor(es, o, 64);
    if (lane == 0) dred[wv] = es;
    __syncthreads();
    if (tid == 0) {
        double z = 0.0;
        for (int i = 0; i < 16; ++i) z += dred[i];
        Ssum[c * 16 + chunk] = z;
        mxkey[c * 16 + chunk] = kmax;
    }
    su[tid] = ((unsigned long long)key << 32) | (unsigned)(~(unsigned)(chunk * 1024 + tid));
    // bitonic sort 1024 descending (composite: value desc, index asc)
    for (int k = 2; k <= 1024; k <<= 1) {
        for (int j = k >> 1; j > 0; j >>= 1) {
            __syncthreads();
            const int i = tid, l = i ^ j;
            if (l > i && i < 1024) {
                unsigned long long a = su[i], b2 = su[l];
                const bool desc = ((i & k) == 0);
                if (desc ? (a < b2) : (a > b2)) { su[i] = b2; su[l] = a; }
            }
        }
    }
    __syncthreads();
    if (tid < 128) cand[(size_t)(c * 16 + chunk) * 128 + tid] = su[tid];
}

// ============ kernel 2: merge candidates -> top-128, Aw; gather rows; wsum w ============
// grid 8 blocks (one per cluster) x 1024 threads
__global__ __launch_bounds__(1024) void merge_gw_kernel(
    const float* __restrict__ feats,
    const unsigned long long* __restrict__ cand,  // [C][2048]
    const unsigned* __restrict__ mxkey,           // [C][16]
    const double* __restrict__ Ssum,              // [C][16]
    float* __restrict__ out,                      // rows at offset 0
    double* __restrict__ w)                       // [C][D]
{
    const int c = blockIdx.x;
    const int tid = threadIdx.x;
    const int lane = tid & 63, wv = tid >> 6;

    __shared__ __align__(16) char mbuf[32768];    // su2 (16KB) | wred (32KB)
    unsigned long long* su2 = (unsigned long long*)mbuf;
    double* wred = (double*)mbuf;
    __shared__ double pd[K_TOP];
    __shared__ double sa[K_TOP];
    __shared__ int sidx[K_TOP];
    __shared__ double dred2[2];
    __shared__ double sZ;

    su2[tid]        = cand[(size_t)c * 2048 + tid];
    su2[tid + 1024] = cand[(size_t)c * 2048 + tid + 1024];
    // bitonic sort 2048 descending
    for (int k = 2; k <= 2048; k <<= 1) {
        for (int j = k >> 1; j > 0; j >>= 1) {
            __syncthreads();
#pragma unroll
            for (int base = 0; base < 2048; base += 1024) {
                const int i = base + tid, l = i ^ j;
                if (l > i) {
                    unsigned long long a = su2[i], b2 = su2[l];
                    const bool desc = ((i & k) == 0);
                    if (desc ? (a < b2) : (a > b2)) { su2[i] = b2; su2[l] = a; }
                }
            }
        }
    }
    __syncthreads();

    const double m_t = (double)key2f((unsigned)(su2[0] >> 32)) * INV_S128;
    if (wv == 0) {   // Z = sum over chunks of Ssum * exp(mx_chunk - m_global)
        double z = (lane < 16)
            ? Ssum[c * 16 + lane] * exp((double)key2f(mxkey[c * 16 + lane]) * INV_S128 - m_t)
            : 0.0;
#pragma unroll
        for (int o = 32; o > 0; o >>= 1) z += __shfl_xor(z, o, 64);
        if (lane == 0) sZ = z;
    }
    __syncthreads();
    const double Z = sZ;
    if (tid < K_TOP) {
        unsigned long long pr = su2[tid];
        sidx[tid] = (int)(~(unsigned)(pr & 0xFFFFFFFFull));
        pd[tid] = exp((double)key2f((unsigned)(pr >> 32)) * INV_S128 - m_t) / Z;
    }
    __syncthreads();
    if (tid < K_TOP) {
        double e = exp((pd[tid] - pd[0]) * INV_S1024);   // pd[0] is max (sorted)
        double se = e;
#pragma unroll
        for (int o = 32; o > 0; o >>= 1) se += __shfl_xor(se, o, 64);
        if (lane == 0) dred2[wv] = se;
    }
    __syncthreads();
    if (tid < K_TOP) {
        double tot = dred2[0] + dred2[1];
        sa[tid] = exp((pd[tid] - pd[0]) * INV_S1024) / tot;
    }
    __syncthreads();

    // ---- fused gather + weighted sum (4 rows in flight; su2 region dead -> wred) ----
    const int g = tid >> 8, q = tid & 255;
    const float* fc = feats + (size_t)c * N_PAT * D_FEAT;
    float* oc = out + (size_t)c * K_TOP * D_FEAT;
    double a0 = 0.0, a1 = 0.0, a2 = 0.0, a3 = 0.0;
    for (int ig = 0; ig < 32; ++ig) {
        const int i = ig * 4 + g;
        const int row = sidx[i];
        float4 v = ((const float4*)(fc + (size_t)row * D_FEAT))[q];
        ((float4*)(oc + (size_t)i * D_FEAT))[q] = v;
        const double a = sa[i];
        a0 += a * (double)v.x;
        a1 += a * (double)v.y;
        a2 += a * (double)v.z;
        a3 += a * (double)v.w;
    }
    wred[(size_t)(g * 256 + q) * 4 + 0] = a0;
    wred[(size_t)(g * 256 + q) * 4 + 1] = a1;
    wred[(size_t)(g * 256 + q) * 4 + 2] = a2;
    wred[(size_t)(g * 256 + q) * 4 + 3] = a3;
    __syncthreads();
    {
        const int d = tid, q2 = d >> 2, j2 = d & 3;
        double s = wred[(0 * 256 + q2) * 4 + j2] + wred[(1 * 256 + q2) * 4 + j2]
                 + wred[(2 * 256 + q2) * 4 + j2] + wred[(3 * 256 + q2) * 4 + j2];
        w[c * D_FEAT + d] = s;
    }
}

// ============ kernel 3: fusion = w @ Wv + bv (in-block split-K) ============
// grid: C * 8(dp-chunks of 128) = 64 blocks x 256 thr
__global__ __launch_bounds__(256) void fusion_kernel(
    const double* __restrict__ w,         // [C][D]
    const float* __restrict__ Wv,         // [D,D]
    const float* __restrict__ bv,         // [D]
    float* __restrict__ out)              // fusion at offset C*K*D
{
    __shared__ double w_lds[D_FEAT];
    __shared__ double partl[2][128];
    const int b = blockIdx.x;
    const int c = b >> 3, dpg = b & 7;
    const int tid = threadIdx.x;           // 256

    for (int d = tid; d < D_FEAT; d += 256) w_lds[d] = w[c * D_FEAT + d];
    __syncthreads();

    const int dpl = tid & 127, half = tid >> 7;
    const int dp = dpg * 128 + dpl;
    const double* wc = w_lds + half * 512;
    const float* wvp = Wv + (size_t)(half * 512) * D_FEAT + dp;
    double a0 = 0.0, a1 = 0.0, a2 = 0.0, a3 = 0.0;
#pragma unroll 2
    for (int d = 0; d < 512; d += 4) {
        a0 += wc[d + 0] * (double)wvp[(size_t)(d + 0) * D_FEAT];
        a1 += wc[d + 1] * (double)wvp[(size_t)(d + 1) * D_FEAT];
        a2 += wc[d + 2] * (double)wvp[(size_t)(d + 2) * D_FEAT];
        a3 += wc[d + 3] * (double)wvp[(size_t)(d + 3) * D_FEAT];
    }
    partl[half][dpl] = (a0 + a1) + (a2 + a3);
    __syncthreads();
    if (half == 0) {
        double acc = (double)bv[dp] + partl[0][dpl] + partl[1][dpl];
        out[(size_t)(C_CLUST * K_TOP * D_FEAT) + c * D_FEAT + dp] = (float)acc;
    }
}

extern "C" void kernel_launch(void* const* d_in, const int* in_sizes, int n_in,
                              void* d_out, int out_size, void* d_ws, size_t ws_size,
                              hipStream_t stream) {
    const float* feats     = (const float*)d_in[0];  // [8,16384,1024]
    const float* key_feats = (const float*)d_in[1];  // [8,1,1024]
    const float* Wq        = (const float*)d_in[2];  // [1024,128]
    const float* bq        = (const float*)d_in[3];  // [128]
    const float* Wv        = (const float*)d_in[4];  // [1024,1024]
    const float* bv        = (const float*)d_in[5];  // [1024]
    float* out = (float*)d_out;

    char* ws = (char*)d_ws;
    unsigned long long* cand = (unsigned long long*)(ws + 0);   // 8*2048*8 = 131072
    double*   Ssum  = (double*)(ws + 131072);                   // 8*16*8   = 1024
    unsigned* mxkey = (unsigned*)(ws + 132096);                 // 8*16*4   = 512
    double*   w     = (double*)(ws + 132608);                   // 8*1024*8 = 65536  (end 198144)

    hipLaunchKernelGGL(scoreall_kernel, dim3(128), dim3(1024), 0, stream,
                       feats, key_feats, Wq, bq, cand, mxkey, Ssum);
    hipLaunchKernelGGL(merge_gw_kernel, dim3(C_CLUST), dim3(1024), 0, stream,
                       feats, cand, mxkey, Ssum, out, w);
    hipLaunchKernelGGL(fusion_kernel,   dim3(64), dim3(256), 0, stream,
                       w, Wv, bv, out);
}

// Round 10
// 241.157 us; speedup vs baseline: 2.3112x; 1.1066x over previous
//
#include <hip/hip_runtime.h>

#define C_CLUST 8
#define N_PAT   16384
#define D_FEAT  1024
#define DQ_DIM  128
#define K_TOP   128
#define NCHUNK  32          // chunks per cluster (512 rows each)
#define CHROWS  512

// 1/sqrt(128) and 1/sqrt(1024)
#define INV_S128 0.08838834764831844055
#define INV_S1024 0.03125

// ---------- helpers ----------
__device__ inline unsigned f2key(float f) {
    unsigned u = __float_as_uint(f);
    return (u & 0x80000000u) ? ~u : (u | 0x80000000u);
}
__device__ inline float key2f(unsigned k) {
    unsigned u = (k & 0x80000000u) ? (k ^ 0x80000000u) : ~k;
    return __uint_as_float(u);
}

// ============ kernel 1: prep(qk,b0,r) + score 512-row chunk + chunk top-128 ============
// grid 256 blocks: b = c*32 + chunk ; 1024 threads (16 waves) ; 1 block per CU
__global__ __launch_bounds__(1024) void scoreall_kernel(
    const float* __restrict__ feats,         // [C,N,D]
    const float* __restrict__ key_feats,     // [C,1,D]
    const float* __restrict__ Wq,            // [D,DQ]
    const float* __restrict__ bq,            // [DQ]
    unsigned long long* __restrict__ cand,   // [C][32][128]
    unsigned* __restrict__ mxkey,            // [C][32]
    double* __restrict__ Ssum)               // [C][32]
{
    const int b = blockIdx.x;
    const int c = b >> 5, chunk = b & 31;
    const int tid = threadIdx.x;
    const int lane = tid & 63, wv = tid >> 6;   // 16 waves

    __shared__ float keyrow[D_FEAT];            // 4 KB
    __shared__ double part[1024];               // 8 KB scratch
    __shared__ double qk_lds[DQ_DIM];           // 1 KB
    __shared__ double r_lds[D_FEAT];            // 8 KB
    __shared__ double b0_lds;
    __shared__ unsigned ured[8];
    __shared__ double dred[8];
    __shared__ unsigned bmax_s;
    __shared__ __align__(16) char ubuf[32768];  // A: Wq tile (32KB) | B: scores(2KB)+su(4KB)
    float* wq_tile  = (float*)ubuf;
    float* scores_s = (float*)ubuf;
    unsigned long long* su = (unsigned long long*)(ubuf + 2048);

    keyrow[tid] = key_feats[c * D_FEAT + tid];
    __syncthreads();

    // ---- qk[j] = key . Wq[:,j] + bq[j]  (8-way split-d partials) ----
    {
        const int j = tid & 127, s = tid >> 7;
        double acc = 0.0;
        for (int d = s; d < D_FEAT; d += 8)
            acc += (double)keyrow[d] * (double)Wq[d * DQ_DIM + j];
        part[s * DQ_DIM + j] = acc;
    }
    __syncthreads();
    if (tid < DQ_DIM) {
        double v = part[tid];
#pragma unroll
        for (int s2 = 1; s2 < 8; ++s2) v += part[s2 * DQ_DIM + tid];
        qk_lds[tid] = v + (double)bq[tid];
    }
    __syncthreads();
    if (wv == 0) {   // b0 = bq . qk
        double p = (double)bq[lane] * qk_lds[lane] + (double)bq[64 + lane] * qk_lds[64 + lane];
#pragma unroll
        for (int o = 32; o > 0; o >>= 1) p += __shfl_xor(p, o, 64);
        if (lane == 0) b0_lds = p;
    }

    // ---- r = Wq @ qk via 16 LDS-staged 64x128 tiles ----
    for (int ch = 0; ch < 16; ++ch) {
        __syncthreads();
        {   // coalesced tile load: 8192 f32 = 2 float4 per thread
            const float4* src = (const float4*)(Wq + (size_t)ch * 64 * DQ_DIM);
            float4* dst = (float4*)wq_tile;
            dst[tid * 2 + 0] = src[tid * 2 + 0];
            dst[tid * 2 + 1] = src[tid * 2 + 1];
        }
        __syncthreads();
        const int dloc = tid >> 4, jg = tid & 15;
        double acc = 0.0;
#pragma unroll
        for (int jj = 0; jj < 8; ++jj)
            acc += (double)wq_tile[dloc * DQ_DIM + jg * 8 + jj] * qk_lds[jg * 8 + jj];
        part[dloc * 16 + jg] = acc;
        __syncthreads();
        if (tid < 64) {
            double s = 0.0;
#pragma unroll
            for (int g = 0; g < 16; ++g) s += part[tid * 16 + g];
            r_lds[ch * 64 + tid] = s;
        }
    }
    __syncthreads();

    // ---- score phase: wave wv -> rows [chunk*512 + wv*32, +32) ----
    const double bb = b0_lds;
    double rr[16];
#pragma unroll
    for (int it = 0; it < 4; ++it)
#pragma unroll
        for (int j = 0; j < 4; ++j)
            rr[it * 4 + j] = r_lds[it * 256 + lane * 4 + j];
    const int n0 = chunk * CHROWS + wv * 32;
    const float4* fbase = (const float4*)(feats + (size_t)(c * N_PAT + n0) * D_FEAT);

    for (int rI = 0; rI < 32; rI += 2) {
        const float4* fp0 = fbase + (size_t)(rI + 0) * 256;
        const float4* fp1 = fbase + (size_t)(rI + 1) * 256;
        double acc0 = 0.0, acc1 = 0.0;
#pragma unroll
        for (int it = 0; it < 4; ++it) {
            float4 f0 = fp0[it * 64 + lane];
            float4 f1 = fp1[it * 64 + lane];
            acc0 += (double)f0.x * rr[it * 4 + 0];
            acc0 += (double)f0.y * rr[it * 4 + 1];
            acc0 += (double)f0.z * rr[it * 4 + 2];
            acc0 += (double)f0.w * rr[it * 4 + 3];
            acc1 += (double)f1.x * rr[it * 4 + 0];
            acc1 += (double)f1.y * rr[it * 4 + 1];
            acc1 += (double)f1.z * rr[it * 4 + 2];
            acc1 += (double)f1.w * rr[it * 4 + 3];
        }
#pragma unroll
        for (int o = 32; o > 0; o >>= 1) {
            acc0 += __shfl_xor(acc0, o, 64);
            acc1 += __shfl_xor(acc1, o, 64);
        }
        if (lane == 0) {
            scores_s[wv * 32 + rI + 0] = (float)(acc0 + bb);
            scores_s[wv * 32 + rI + 1] = (float)(acc1 + bb);
        }
    }
    __syncthreads();

    // ---- chunk softmax partials + top-128 of 512 (threads 0..511 active) ----
    float sc = 0.0f; unsigned key = 0;
    if (tid < CHROWS) { sc = scores_s[tid]; key = f2key(sc); }
    if (tid < CHROWS) {
        unsigned mk = key;
#pragma unroll
        for (int o = 32; o > 0; o >>= 1) mk = max(mk, __shfl_xor(mk, o, 64));
        if (lane == 0) ured[wv] = mk;
    }
    __syncthreads();
    if (tid == 0) {
        unsigned m = ured[0];
        for (int i = 1; i < 8; ++i) m = max(m, ured[i]);
        bmax_s = m;
    }
    __syncthreads();
    const unsigned kmax = bmax_s;
    const double mx_t = (double)key2f(kmax) * INV_S128;
    if (tid < CHROWS) {
        double es = (double)__expf((float)((double)sc * INV_S128 - mx_t));
#pragma unroll
        for (int o = 32; o > 0; o >>= 1) es += __shfl_xor(es, o, 64);
        if (lane == 0) dred[wv] = es;
    }
    __syncthreads();
    if (tid == 0) {
        double z = 0.0;
        for (int i = 0; i < 8; ++i) z += dred[i];
        Ssum[c * NCHUNK + chunk] = z;
        mxkey[c * NCHUNK + chunk] = kmax;
    }
    if (tid < CHROWS)
        su[tid] = ((unsigned long long)key << 32) | (unsigned)(~(unsigned)(chunk * CHROWS + tid));
    // bitonic sort 512 descending (composite: value desc, index asc)
    for (int k = 2; k <= CHROWS; k <<= 1) {
        for (int j = k >> 1; j > 0; j >>= 1) {
            __syncthreads();
            const int i = tid, l = i ^ j;
            if (i < CHROWS && l > i) {
                unsigned long long a = su[i], b2 = su[l];
                const bool desc = ((i & k) == 0);
                if (desc ? (a < b2) : (a > b2)) { su[i] = b2; su[l] = a; }
            }
        }
    }
    __syncthreads();
    if (tid < K_TOP) cand[(size_t)(c * NCHUNK + chunk) * K_TOP + tid] = su[tid];
}

// ============ kernel 2: tree-merge 32x128 -> top-128, Aw; gather rows; wsum w ============
// grid 8 blocks (one per cluster) x 1024 threads
__global__ __launch_bounds__(1024) void merge_gw_kernel(
    const float* __restrict__ feats,
    const unsigned long long* __restrict__ cand,  // [C][32*128]
    const unsigned* __restrict__ mxkey,           // [C][32]
    const double* __restrict__ Ssum,              // [C][32]
    float* __restrict__ out,                      // rows at offset 0
    double* __restrict__ w)                       // [C][D]
{
    const int c = blockIdx.x;
    const int tid = threadIdx.x;
    const int lane = tid & 63, wv = tid >> 6;

    __shared__ __align__(16) char mbuf[32768];    // su2: 4096 keys (32KB) | later wred (32KB)
    unsigned long long* su2 = (unsigned long long*)mbuf;
    double* wred = (double*)mbuf;
    __shared__ double pd[K_TOP];
    __shared__ double sa[K_TOP];
    __shared__ int sidx[K_TOP];
    __shared__ double dred2[2];
    __shared__ double sZ;

    su2[tid]        = cand[(size_t)c * 4096 + tid];
    su2[tid + 1024] = cand[(size_t)c * 4096 + tid + 1024];
    su2[tid + 2048] = cand[(size_t)c * 4096 + tid + 2048];
    su2[tid + 3072] = cand[(size_t)c * 4096 + tid + 3072];
    __syncthreads();

    // ---- bitonic top-k tree merge: 32 desc-sorted lists of 128 -> top-128 desc ----
    for (int nl = 32; nl > 1; nl >>= 1) {
        const int half = nl >> 1;
        const int total = half * K_TOP;           // outputs this level (<= 2048)
        unsigned long long tmp[2];
        int cnt = 0;
        for (int i = tid; i < total; i += 1024) { // C[i] = max(A[i], B[127-i])
            const int g = i >> 7, li = i & 127;
            unsigned long long a  = su2[(2 * g) * K_TOP + li];
            unsigned long long b2 = su2[(2 * g + 1) * K_TOP + (K_TOP - 1 - li)];
            tmp[cnt++] = a > b2 ? a : b2;
        }
        __syncthreads();
        cnt = 0;
        for (int i = tid; i < total; i += 1024) su2[i] = tmp[cnt++];
        __syncthreads();
        for (int j = 64; j > 0; j >>= 1) {        // clean bitonic 128-lists, desc
            for (int i = tid; i < total; i += 1024) {
                const int li = i & 127, l = li ^ j;
                if (l > li) {
                    const int base = i - li;
                    unsigned long long a = su2[base + li], b2 = su2[base + l];
                    if (a < b2) { su2[base + li] = b2; su2[base + l] = a; }
                }
            }
            __syncthreads();
        }
    }

    const double m_t = (double)key2f((unsigned)(su2[0] >> 32)) * INV_S128;
    if (wv == 0) {   // Z = sum over 32 chunks of Ssum * exp(mx_chunk - m_global)
        double z = (lane < NCHUNK)
            ? Ssum[c * NCHUNK + lane] * exp((double)key2f(mxkey[c * NCHUNK + lane]) * INV_S128 - m_t)
            : 0.0;
#pragma unroll
        for (int o = 32; o > 0; o >>= 1) z += __shfl_xor(z, o, 64);
        if (lane == 0) sZ = z;
    }
    __syncthreads();
    const double Z = sZ;
    if (tid < K_TOP) {
        unsigned long long pr = su2[tid];
        sidx[tid] = (int)(~(unsigned)(pr & 0xFFFFFFFFull));
        pd[tid] = exp((double)key2f((unsigned)(pr >> 32)) * INV_S128 - m_t) / Z;
    }
    __syncthreads();
    if (tid < K_TOP) {
        double e = exp((pd[tid] - pd[0]) * INV_S1024);   // pd[0] is max (sorted)
        double se = e;
#pragma unroll
        for (int o = 32; o > 0; o >>= 1) se += __shfl_xor(se, o, 64);
        if (lane == 0) dred2[wv] = se;
    }
    __syncthreads();
    if (tid < K_TOP) {
        double tot = dred2[0] + dred2[1];
        sa[tid] = exp((pd[tid] - pd[0]) * INV_S1024) / tot;
    }
    __syncthreads();

    // ---- fused gather + weighted sum (4 rows in flight; su2 region dead -> wred) ----
    const int g = tid >> 8, q = tid & 255;
    const float* fc = feats + (size_t)c * N_PAT * D_FEAT;
    float* oc = out + (size_t)c * K_TOP * D_FEAT;
    double a0 = 0.0, a1 = 0.0, a2 = 0.0, a3 = 0.0;
    for (int ig = 0; ig < 32; ++ig) {
        const int i = ig * 4 + g;
        const int row = sidx[i];
        float4 v = ((const float4*)(fc + (size_t)row * D_FEAT))[q];
        ((float4*)(oc + (size_t)i * D_FEAT))[q] = v;
        const double a = sa[i];
        a0 += a * (double)v.x;
        a1 += a * (double)v.y;
        a2 += a * (double)v.z;
        a3 += a * (double)v.w;
    }
    wred[(size_t)(g * 256 + q) * 4 + 0] = a0;
    wred[(size_t)(g * 256 + q) * 4 + 1] = a1;
    wred[(size_t)(g * 256 + q) * 4 + 2] = a2;
    wred[(size_t)(g * 256 + q) * 4 + 3] = a3;
    __syncthreads();
    {
        const int d = tid, q2 = d >> 2, j2 = d & 3;
        double s = wred[(0 * 256 + q2) * 4 + j2] + wred[(1 * 256 + q2) * 4 + j2]
                 + wred[(2 * 256 + q2) * 4 + j2] + wred[(3 * 256 + q2) * 4 + j2];
        w[c * D_FEAT + d] = s;
    }
}

// ============ kernel 3: fusion = w @ Wv + bv (in-block split-K) ============
// grid: C * 8(dp-chunks of 128) = 64 blocks x 256 thr
__global__ __launch_bounds__(256) void fusion_kernel(
    const double* __restrict__ w,         // [C][D]
    const float* __restrict__ Wv,         // [D,D]
    const float* __restrict__ bv,         // [D]
    float* __restrict__ out)              // fusion at offset C*K*D
{
    __shared__ double w_lds[D_FEAT];
    __shared__ double partl[2][128];
    const int b = blockIdx.x;
    const int c = b >> 3, dpg = b & 7;
    const int tid = threadIdx.x;           // 256

    for (int d = tid; d < D_FEAT; d += 256) w_lds[d] = w[c * D_FEAT + d];
    __syncthreads();

    const int dpl = tid & 127, half = tid >> 7;
    const int dp = dpg * 128 + dpl;
    const double* wc = w_lds + half * 512;
    const float* wvp = Wv + (size_t)(half * 512) * D_FEAT + dp;
    double a0 = 0.0, a1 = 0.0, a2 = 0.0, a3 = 0.0;
#pragma unroll 2
    for (int d = 0; d < 512; d += 4) {
        a0 += wc[d + 0] * (double)wvp[(size_t)(d + 0) * D_FEAT];
        a1 += wc[d + 1] * (double)wvp[(size_t)(d + 1) * D_FEAT];
        a2 += wc[d + 2] * (double)wvp[(size_t)(d + 2) * D_FEAT];
        a3 += wc[d + 3] * (double)wvp[(size_t)(d + 3) * D_FEAT];
    }
    partl[half][dpl] = (a0 + a1) + (a2 + a3);
    __syncthreads();
    if (half == 0) {
        double acc = (double)bv[dp] + partl[0][dpl] + partl[1][dpl];
        out[(size_t)(C_CLUST * K_TOP * D_FEAT) + c * D_FEAT + dp] = (float)acc;
    }
}

extern "C" void kernel_launch(void* const* d_in, const int* in_sizes, int n_in,
                              void* d_out, int out_size, void* d_ws, size_t ws_size,
                              hipStream_t stream) {
    const float* feats     = (const float*)d_in[0];  // [8,16384,1024]
    const float* key_feats = (const float*)d_in[1];  // [8,1,1024]
    const float* Wq        = (const float*)d_in[2];  // [1024,128]
    const float* bq        = (const float*)d_in[3];  // [128]
    const float* Wv        = (const float*)d_in[4];  // [1024,1024]
    const float* bv        = (const float*)d_in[5];  // [1024]
    float* out = (float*)d_out;

    char* ws = (char*)d_ws;
    unsigned long long* cand = (unsigned long long*)(ws + 0);   // 8*32*128*8 = 262144
    double*   Ssum  = (double*)(ws + 262144);                   // 8*32*8     = 2048
    unsigned* mxkey = (unsigned*)(ws + 264192);                 // 8*32*4     = 1024
    double*   w     = (double*)(ws + 265216);                   // 8*1024*8   = 65536  (end 330752)

    hipLaunchKernelGGL(scoreall_kernel, dim3(256), dim3(1024), 0, stream,
                       feats, key_feats, Wq, bq, cand, mxkey, Ssum);
    hipLaunchKernelGGL(merge_gw_kernel, dim3(C_CLUST), dim3(1024), 0, stream,
                       feats, cand, mxkey, Ssum, out, w);
    hipLaunchKernelGGL(fusion_kernel,   dim3(64), dim3(256), 0, stream,
                       w, Wv, bv, out);
}